// Round 6
// baseline (190.224 us; speedup 1.0000x reference)
//
#include <hip/hip_runtime.h>
#include <hip/hip_bf16.h>
#include <stdint.h>

#define H_EDGES 4096
#define N_NODES 20000
#define FIN 256
#define FOUT 128
#define DEG 32
#define ROWS_TOTAL 24096      // 4096 + 20000
#define GRID 512
#define GEMM_TILES 377        // ceil(24096 / 64)

typedef float f32x4 __attribute__((ext_vector_type(4)));
typedef short s16x8 __attribute__((ext_vector_type(8)));
typedef unsigned short u16;

__device__ __forceinline__ u16 f2bf(float f) {
    return __builtin_bit_cast(u16, __float2bfloat16(f));   // RNE
}
__device__ __forceinline__ float bf2f(u16 h) {
    unsigned u = ((unsigned)h) << 16;
    return __builtin_bit_cast(float, u);
}

// Device-scope counting barrier. Counters are memset to 0 by kernel_launch
// each call (graph node), so every replay starts clean. All GRID blocks are
// provably co-resident (LDS 42.5KB -> 3 blk/CU, VGPR<=168 via launch_bounds
// -> capacity 768 >= 512). Spin bound turns any residency surprise into a
// wrong answer instead of a hang.
__device__ __forceinline__ void gbar(unsigned* cnt, unsigned target) {
    __syncthreads();
    if (threadIdx.x == 0) {
        __threadfence();   // release our stores (wbL2 at agent scope)
        __hip_atomic_fetch_add(cnt, 1u, __ATOMIC_ACQ_REL, __HIP_MEMORY_SCOPE_AGENT);
        unsigned v; long spins = 0;
        do {
            v = __hip_atomic_load(cnt, __ATOMIC_ACQUIRE, __HIP_MEMORY_SCOPE_AGENT);
            __builtin_amdgcn_s_sleep(2);
        } while (v < target && ++spins < 20000000L);
        __threadfence();   // acquire: invalidate L1/L2 before consuming
    }
    __syncthreads();
}

// bt layout: [col][32 slots of 16B]; slot s (k = s*8..s*8+7) stored at
// col*32 + (s&16) + ((s&15) ^ (col&15))  -> GEMM LDS copies stay linear,
// fragment reads are bank-spread (<=2-way, free).
__global__ __launch_bounds__(256, 3)
void fused(const float* __restrict__ hedge, const float* __restrict__ node,
           const float* __restrict__ Wq, const int* __restrict__ col_idx,
           float* __restrict__ out, float* __restrict__ qf,
           u16* __restrict__ kb, u16* __restrict__ bt, unsigned* __restrict__ bar) {
    __shared__ __align__(16) char smem[42496];
    const int bid = blockIdx.x;
    const int t = threadIdx.x;
    const int w = t >> 6, l = t & 63;
    const int lr = l & 15, lp = l >> 4;

    // ---------------- phase A: build bt (16 blocks) + A-prefetch ------------
    if (bid < 16) {
        const int g = bid * 256 + t;          // 0..4095
        const int col = g >> 5, s = g & 31;
        s16x8 b;
        #pragma unroll
        for (int e = 0; e < 8; ++e)
            b[e] = (short)f2bf(Wq[(size_t)(s * 8 + e) * FOUT + col]);
        const int phys = col * 32 + (s & 16) + ((s & 15) ^ (col & 15));
        *(s16x8*)(bt + (size_t)phys * 8) = b;
    }

    const bool gemmBlk = bid < GEMM_TILES;
    const long rb  = (long)bid * 64 + w * 16;
    f32x4 au[8], av[8];
    if (gemmBlk) {
        const long row  = rb + lr;
        const long arow = row < ROWS_TOTAL ? row : ROWS_TOTAL - 1;  // clamp; OOB never stored
        const float* pa = arow < H_EDGES ? hedge + arow * FIN
                                         : node + (arow - H_EDGES) * FIN;
        #pragma unroll
        for (int ks = 0; ks < 8; ++ks) {      // 16 loads in flight across barrier
            au[ks] = *(const f32x4*)(pa + ks * 32 + lp * 8);
            av[ks] = *(const f32x4*)(pa + ks * 32 + lp * 8 + 4);
        }
    }

    gbar(bar + 0, GRID);

    // ---------------- phase B: GEMM (wave = 16 rows x 128 cols) -------------
    if (gemmBlk) {
        u16* blds = (u16*)smem;               // 32 KB: one K-half of B
        f32x4 acc[8];
        #pragma unroll
        for (int j = 0; j < 8; ++j) acc[j] = (f32x4){0.f, 0.f, 0.f, 0.f};

        #pragma unroll
        for (int kh = 0; kh < 2; ++kh) {
            #pragma unroll
            for (int j = 0; j < 8; ++j) {     // stage 2048 16B slots, coalesced
                const int idx = t + 256 * j;
                *(s16x8*)(blds + (size_t)idx * 8) =
                    *(const s16x8*)(bt + (size_t)((idx >> 4) * 32 + kh * 16 + (idx & 15)) * 8);
            }
            __syncthreads();
            #pragma unroll
            for (int ks2 = 0; ks2 < 4; ++ks2) {
                const int ks = kh * 4 + ks2;
                s16x8 a;
                #pragma unroll
                for (int j = 0; j < 4; ++j) {
                    a[j]     = (short)f2bf(au[ks][j]);
                    a[j + 4] = (short)f2bf(av[ks][j]);
                }
                #pragma unroll
                for (int cf = 0; cf < 8; ++cf) {
                    const int col = cf * 16 + lr;
                    s16x8 b = *(const s16x8*)(blds +
                        (size_t)(col * 16 + ((ks2 * 4 + lp) ^ (col & 15))) * 8);
                    acc[cf] = __builtin_amdgcn_mfma_f32_16x16x32_bf16(a, b, acc[cf], 0, 0, 0);
                }
            }
            __syncthreads();
        }

        // epilogue: D map row=lp*4+i, col=lr. rb<H_EDGES is wave-uniform.
        if (rb < H_EDGES) {
            #pragma unroll
            for (int i = 0; i < 4; ++i) {
                const long gr = rb + lp * 4 + i;
                #pragma unroll
                for (int cf = 0; cf < 8; ++cf)
                    qf[gr * FOUT + cf * 16 + lr] = acc[cf][i];
            }
        } else {
            #pragma unroll
            for (int i = 0; i < 4; ++i) {
                const long gr = rb + lp * 4 + i;
                if (gr < ROWS_TOTAL) {
                    #pragma unroll
                    for (int cf = 0; cf < 8; ++cf)
                        kb[(gr - H_EDGES) * FOUT + cf * 16 + lr] = f2bf(acc[cf][i]);
                }
            }
        }
    }

    gbar(bar + 1, GRID);

    // ---------------- phase C: attention, 8 edges/block (2 per wave) --------
    float (*tile)[9] = (float(*)[9])smem;         // [128][9] f32 = 4608 B
    char* base = smem + 4608 + w * 9472;          // per-wave slice
    u16 (*k_l)[136] = (u16(*)[136])base;          // 32 x 136 u16 = 8704 B
    float* q_l = (float*)(base + 8704);           // 128 f32
    float* w_l = q_l + 128;                       // 32 f32
    int*   c_l = (int*)(w_l + 32);                // 32 int

    #pragma unroll
    for (int i = 0; i < 2; ++i) {
        const int e = bid * 8 + w * 2 + i;
        if (l < DEG) c_l[l] = col_idx[(size_t)e * DEG + l];
        q_l[l]      = qf[(size_t)e * FOUT + l];
        q_l[l + 64] = qf[(size_t)e * FOUT + 64 + l];
        __syncthreads();

        #pragma unroll
        for (int it = 0; it < 8; ++it) {          // gather 32 rows x 256 B
            const int s = l + 64 * it;
            const int m = s >> 4, sl = s & 15;
            *(s16x8*)&k_l[m][sl * 8] =
                *(const s16x8*)(kb + (size_t)c_l[m] * FOUT + sl * 8);
        }
        __syncthreads();

        // scores: 2 lanes per member, 64 elems each
        const int m = l >> 1, he = l & 1;
        float p = 0.f;
        #pragma unroll
        for (int j = 0; j < 8; ++j) {
            s16x8 kv = *(const s16x8*)&k_l[m][he * 64 + j * 8];
            #pragma unroll
            for (int ee = 0; ee < 8; ++ee)
                p = fmaf(q_l[he * 64 + j * 8 + ee], bf2f((u16)kv[ee]), p);
        }
        p += __shfl_xor(p, 1);
        const float sc = p * 0.08838834764831845f;   // 1/sqrt(128)

        // dedup (first occurrence only) + softmax; pair lanes duplicate
        const int cm = c_l[m];
        bool valid = true;
        for (int j = 0; j < m; ++j)
            if (c_l[j] == cm) valid = false;
        const float sv = valid ? sc : -INFINITY;
        float mx = sv;
        #pragma unroll
        for (int d = 1; d < 64; d <<= 1) mx = fmaxf(mx, __shfl_xor(mx, d));
        const float ex = valid ? __expf(sv - mx) : 0.f;
        float sum = ex;
        #pragma unroll
        for (int d = 1; d < 64; d <<= 1) sum += __shfl_xor(sum, d);
        if (he == 0) w_l[m] = ex * 2.f / sum;        // 64-lane sum double-counts pairs
        __syncthreads();

        float a0 = 0.f, a1 = 0.f;
        #pragma unroll
        for (int mm = 0; mm < DEG; ++mm) {
            const float wv = w_l[mm];
            a0 = fmaf(wv, bf2f(k_l[mm][l]), a0);
            a1 = fmaf(wv, bf2f(k_l[mm][l + 64]), a1);
        }
        tile[l][w * 2 + i]      = a0;                // disjoint columns per (w,i)
        tile[l + 64][w * 2 + i] = a1;
        __syncthreads();
    }

    // fused transpose store: out[f][bid*8 .. bid*8+7]
    if (t < FOUT) {
        f32x4 v0 = {tile[t][0], tile[t][1], tile[t][2], tile[t][3]};
        f32x4 v1 = {tile[t][4], tile[t][5], tile[t][6], tile[t][7]};
        float* dst = out + (size_t)t * H_EDGES + (size_t)bid * 8;
        *(f32x4*)dst       = v0;
        *(f32x4*)(dst + 4) = v1;
    }
}

extern "C" void kernel_launch(void* const* d_in, const int* in_sizes, int n_in,
                              void* d_out, int out_size, void* d_ws, size_t ws_size,
                              hipStream_t stream) {
    const float* hedge   = (const float*)d_in[0];
    const float* node    = (const float*)d_in[1];
    const float* Wq      = (const float*)d_in[2];
    const int*   col_idx = (const int*)d_in[4];   // row_idx (d_in[3]) == e/DEG by construction
    float* out = (float*)d_out;

    char* ws = (char*)d_ws;
    float*    qf  = (float*)ws;                                   // 2 MB
    u16*      kb  = (u16*)(ws + (size_t)H_EDGES * FOUT * 4);      // 5.12 MB
    u16*      bt  = (u16*)(ws + (size_t)H_EDGES * FOUT * 4
                              + (size_t)N_NODES * FOUT * 2);      // 64 KB
    unsigned* bar = (unsigned*)(ws + (size_t)H_EDGES * FOUT * 4
                                   + (size_t)N_NODES * FOUT * 2
                                   + (size_t)FOUT * FIN * 2);     // 2 counters

    hipMemsetAsync(bar, 0, 64, stream);
    fused<<<GRID, 256, 0, stream>>>(hedge, node, Wq, col_idx, out, qf, kb, bt, bar);
}

// Round 7
// 170.398 us; speedup vs baseline: 1.1164x; 1.1164x over previous
//
#include <hip/hip_runtime.h>
#include <hip/hip_bf16.h>
#include <stdint.h>

#define H_EDGES 4096
#define N_NODES 20000
#define FIN 256
#define FOUT 128
#define DEG 32
#define ROWS_TOTAL 24096      // 4096 + 20000
#define G1_BLOCKS 377         // ceil(24096 / 64)
#define REP1 16               // diagnostic repeat factors (idempotent)
#define REP2 16

typedef float f32x4 __attribute__((ext_vector_type(4)));
typedef short s16x8 __attribute__((ext_vector_type(8)));
typedef unsigned short u16;

__device__ __forceinline__ u16 f2bf(float f) {
    return __builtin_bit_cast(u16, __float2bfloat16(f));   // RNE
}
__device__ __forceinline__ float bf2f(u16 h) {
    unsigned u = ((unsigned)h) << 16;
    return __builtin_bit_cast(float, u);
}

// ---------- g1: [hedge;node] @ Wq via bf16 MFMA (x REP1 diagnostic) --------
__global__ __launch_bounds__(256)
void g1_gemm(const float* __restrict__ hedge, const float* __restrict__ node,
             const float* __restrict__ Wq, float* __restrict__ qf,
             u16* __restrict__ kb) {
    __shared__ u16 blds[FOUT * FIN];   // 64 KB
    const int t = threadIdx.x;
    const int w = t >> 6, l = t & 63;
    const int lr = l & 15, lp = l >> 4;
    const long rb  = (long)blockIdx.x * 64 + w * 16;
    const long row = rb + lr;
    const long arow = row < ROWS_TOTAL ? row : ROWS_TOTAL - 1;  // clamp; OOB never stored
    const float* pa = arow < H_EDGES ? hedge + arow * FIN
                                     : node + (arow - H_EDGES) * FIN;

    #pragma unroll 1
    for (int rep = 0; rep < REP1; ++rep) {
        // A: issue all 16 global loads up-front
        f32x4 au[8], av[8];
        #pragma unroll
        for (int ks = 0; ks < 8; ++ks) {
            au[ks] = *(const f32x4*)(pa + ks * 32 + lp * 8);
            av[ks] = *(const f32x4*)(pa + ks * 32 + lp * 8 + 4);
        }

        // B build: thread t -> col = t>>1, slots (t&1)*16 .. +15
        {
            const int col   = t >> 1;
            const int sbase = (t & 1) * 16;
            #pragma unroll
            for (int j = 0; j < 16; ++j) {
                const int s  = sbase + j;
                const int k0 = s * 8;
                s16x8 b;
                #pragma unroll
                for (int e = 0; e < 8; ++e)
                    b[e] = (short)f2bf(Wq[(size_t)(k0 + e) * FOUT + col]);
                *(s16x8*)(blds + (size_t)(col * 32 + (s ^ (col & 7))) * 8) = b;
            }
        }
        __syncthreads();

        f32x4 acc[8];
        #pragma unroll
        for (int j = 0; j < 8; ++j) acc[j] = (f32x4){0.f, 0.f, 0.f, 0.f};

        #pragma unroll
        for (int ks = 0; ks < 8; ++ks) {
            s16x8 a;
            #pragma unroll
            for (int j = 0; j < 4; ++j) {
                a[j]     = (short)f2bf(au[ks][j]);
                a[j + 4] = (short)f2bf(av[ks][j]);
            }
            #pragma unroll
            for (int cf = 0; cf < 8; ++cf) {
                const int col = cf * 16 + lr;
                s16x8 b = *(const s16x8*)(blds +
                    (size_t)(col * 32 + ((ks * 4 + lp) ^ (col & 7))) * 8);
                acc[cf] = __builtin_amdgcn_mfma_f32_16x16x32_bf16(a, b, acc[cf], 0, 0, 0);
            }
        }

        // epilogue: D map row=lp*4+i, col=lr. rb<H_EDGES is wave-uniform.
        if (rb < H_EDGES) {
            #pragma unroll
            for (int i = 0; i < 4; ++i) {
                const long gr = rb + lp * 4 + i;
                #pragma unroll
                for (int cf = 0; cf < 8; ++cf)
                    qf[gr * FOUT + cf * 16 + lr] = acc[cf][i];
            }
        } else {
            #pragma unroll
            for (int i = 0; i < 4; ++i) {
                const long gr = rb + lp * 4 + i;
                if (gr < ROWS_TOTAL) {
                    #pragma unroll
                    for (int cf = 0; cf < 8; ++cf)
                        kb[(gr - H_EDGES) * FOUT + cf * 16 + lr] = f2bf(acc[cf][i]);
                }
            }
        }
        __syncthreads();   // rep-safety: no overwrite while readers in flight
    }
}

// ---------- g2: per-edge attention + fused transposed store (x REP2) -------
// 1024 blocks x 256 thr = 4 edges/block, one 64-lane wave per edge.
// tile region disjoint from per-wave slices so the rep loop is race-free.
__global__ __launch_bounds__(256)
void g2_attn(const float* __restrict__ qf, const u16* __restrict__ kb,
             const int* __restrict__ col_idx, float* __restrict__ out) {
    __shared__ __align__(16) char smem[39936];
    const int t = threadIdx.x;
    const int w = t >> 6, l = t & 63;
    const int e = blockIdx.x * 4 + w;

    float (*tile)[4] = (float(*)[4])smem;         // [128][4] f32 = 2048 B
    char* base = smem + 2048 + w * 9472;          // per-wave slice
    u16 (*k_l)[136] = (u16(*)[136])base;          // 32 x 136 u16 = 8704 B
    float* q_l = (float*)(base + 8704);           // 128 f32
    float* w_l = q_l + 128;                       // 32 f32
    int*   c_l = (int*)(w_l + 32);                // 32 int

    #pragma unroll 1
    for (int rep = 0; rep < REP2; ++rep) {
        if (l < DEG) c_l[l] = col_idx[(size_t)e * DEG + l];
        q_l[l]      = qf[(size_t)e * FOUT + l];
        q_l[l + 64] = qf[(size_t)e * FOUT + 64 + l];
        __syncthreads();

        #pragma unroll
        for (int it = 0; it < 8; ++it) {          // gather 32 rows x 256 B
            const int s = l + 64 * it;
            const int m = s >> 4, sl = s & 15;
            *(s16x8*)&k_l[m][sl * 8] =
                *(const s16x8*)(kb + (size_t)c_l[m] * FOUT + sl * 8);
        }
        __syncthreads();

        // scores: 2 lanes per member, 64 elems each
        const int m = l >> 1, he = l & 1;
        float p = 0.f;
        #pragma unroll
        for (int j = 0; j < 8; ++j) {
            s16x8 kv = *(const s16x8*)&k_l[m][he * 64 + j * 8];
            #pragma unroll
            for (int ee = 0; ee < 8; ++ee)
                p = fmaf(q_l[he * 64 + j * 8 + ee], bf2f((u16)kv[ee]), p);
        }
        p += __shfl_xor(p, 1);
        const float sc = p * 0.08838834764831845f;    // 1/sqrt(128)

        // dedup (first occurrence only) + softmax; pair lanes duplicate
        const int cm = c_l[m];
        bool valid = true;
        for (int j = 0; j < m; ++j)
            if (c_l[j] == cm) valid = false;
        const float sv = valid ? sc : -INFINITY;
        float mx = sv;
        #pragma unroll
        for (int d = 1; d < 64; d <<= 1) mx = fmaxf(mx, __shfl_xor(mx, d));
        const float ex = valid ? __expf(sv - mx) : 0.f;
        float sum = ex;
        #pragma unroll
        for (int d = 1; d < 64; d <<= 1) sum += __shfl_xor(sum, d);
        if (he == 0) w_l[m] = ex * 2.f / sum;         // 64-lane sum double-counts pairs
        __syncthreads();

        float a0 = 0.f, a1 = 0.f;
        #pragma unroll
        for (int mm = 0; mm < DEG; ++mm) {
            const float wv = w_l[mm];
            a0 = fmaf(wv, bf2f(k_l[mm][l]), a0);
            a1 = fmaf(wv, bf2f(k_l[mm][l + 64]), a1);
        }

        // micro-transpose: tile[f][edge-in-block], then float4 rows to out
        tile[l][w]      = a0;
        tile[l + 64][w] = a1;
        __syncthreads();
        if (t < FOUT) {
            f32x4 v = *(const f32x4*)tile[t];
            *(f32x4*)(out + (size_t)t * H_EDGES + blockIdx.x * 4) = v;
        }
        __syncthreads();   // rep-safety: tile reads done before next overwrite
    }
}

extern "C" void kernel_launch(void* const* d_in, const int* in_sizes, int n_in,
                              void* d_out, int out_size, void* d_ws, size_t ws_size,
                              hipStream_t stream) {
    const float* hedge   = (const float*)d_in[0];
    const float* node    = (const float*)d_in[1];
    const float* Wq      = (const float*)d_in[2];
    const int*   col_idx = (const int*)d_in[4];   // row_idx (d_in[3]) == e/DEG by construction
    float* out = (float*)d_out;

    char* ws = (char*)d_ws;
    float* qf = (float*)ws;                                  // 4096*128 f32  = 2 MB
    u16*   kb = (u16*)(ws + (size_t)H_EDGES * FOUT * 4);     // 20000*128 bf16 = 5.12 MB

    g1_gemm<<<G1_BLOCKS, 256, 0, stream>>>(hedge, node, Wq, qf, kb);
    g2_attn<<<H_EDGES / 4, 256, 0, stream>>>(qf, kb, col_idx, out);
}

// Round 8
// 31.275 us; speedup vs baseline: 6.0823x; 5.4483x over previous
//
#include <hip/hip_runtime.h>
#include <hip/hip_bf16.h>
#include <stdint.h>

#define H_EDGES 4096
#define N_NODES 20000
#define FIN 256
#define FOUT 128
#define DEG 32
#define ROWS_TOTAL 24096      // 4096 + 20000
#define G1_BLOCKS 377         // ceil(24096 / 64)

typedef float f32x4 __attribute__((ext_vector_type(4)));
typedef short s16x8 __attribute__((ext_vector_type(8)));
typedef unsigned short u16;

__device__ __forceinline__ u16 f2bf(float f) {
    return __builtin_bit_cast(u16, __float2bfloat16(f));   // RNE
}
__device__ __forceinline__ float bf2f(u16 h) {
    unsigned u = ((unsigned)h) << 16;
    return __builtin_bit_cast(float, u);
}

// ---------- k0: Wq fp32 [256][128] -> bt bf16 [col][slot] (COALESCED) ------
// bt: col-row of 32 16B slots; slot s holds k=s*8..s*8+7, stored at
// phys = s ^ (col&7)  (XOR low-3: bank-spread for g1's fragment reads while
// g1's LDS staging copy stays linear).
// 16 blocks: tile = 64 k x 32 col. Coalesced row-major Wq reads; LDS
// transpose; 16B coalesced bt writes. Kills the column-read line storm.
__global__ __launch_bounds__(256)
void k0_prep(const float* __restrict__ Wq, u16* __restrict__ bt) {
    __shared__ u16 lt[32][72];            // [col_local][k_local], stride 144B
    const int t  = threadIdx.x;
    const int kt = blockIdx.x >> 2;       // 0..3 -> k0 = kt*64
    const int ct = blockIdx.x & 3;        // 0..3 -> c0 = ct*32
    const int k0 = kt * 64, c0 = ct * 32;

    #pragma unroll
    for (int p = 0; p < 2; ++p) {         // 2 passes x 32 rows
        const int r = p * 32 + (t >> 3);  // k_local 0..63
        const int q = t & 7;              // col quad 0..7
        f32x4 v = *(const f32x4*)(Wq + (size_t)(k0 + r) * FOUT + c0 + q * 4);
        #pragma unroll
        for (int j = 0; j < 4; ++j) lt[q * 4 + j][r] = f2bf(v[j]);
    }
    __syncthreads();

    const int cl = t >> 3;                // col_local 0..31
    const int sl = t & 7;                 // slot-in-tile 0..7
    const int col = c0 + cl;
    const int s_glob = kt * 8 + sl;
    const int phys = s_glob ^ (col & 7);
    *(s16x8*)(bt + (size_t)(col * 32 + phys) * 8) = *(const s16x8*)&lt[cl][sl * 8];
}

// ---------- g1: [hedge;node] @ Wq via bf16 MFMA ----------------------------
// 377 blocks x 256 thr (4 waves). Block = 64 rows x 128 cols; full B staged
// bt->LDS as a LINEAR coalesced b128 copy (bt pre-swizzled by k0).
__global__ __launch_bounds__(256)
void g1_gemm(const float* __restrict__ hedge, const float* __restrict__ node,
             const u16* __restrict__ bt, float* __restrict__ qf,
             u16* __restrict__ kb) {
    __shared__ u16 blds[FOUT * FIN];      // 64 KB
    const int t = threadIdx.x;
    const int w = t >> 6, l = t & 63;
    const int lr = l & 15, lp = l >> 4;
    const long rb  = (long)blockIdx.x * 64 + w * 16;
    const long row = rb + lr;
    const long arow = row < ROWS_TOTAL ? row : ROWS_TOTAL - 1;  // clamp; OOB never stored
    const float* pa = arow < H_EDGES ? hedge + arow * FIN
                                     : node + (arow - H_EDGES) * FIN;

    // A: issue all 16 HBM loads up-front (they drain under the B staging)
    f32x4 au[8], av[8];
    #pragma unroll
    for (int ks = 0; ks < 8; ++ks) {
        au[ks] = *(const f32x4*)(pa + ks * 32 + lp * 8);
        av[ks] = *(const f32x4*)(pa + ks * 32 + lp * 8 + 4);
    }

    // B: linear coalesced copy (16 x b128 per thread, L2-resident source)
    {
        const s16x8* src = (const s16x8*)bt;
        s16x8* dst = (s16x8*)blds;
        #pragma unroll
        for (int j = 0; j < 16; ++j) { const int s = t + 256 * j; dst[s] = src[s]; }
    }
    __syncthreads();

    f32x4 acc[8];
    #pragma unroll
    for (int j = 0; j < 8; ++j) acc[j] = (f32x4){0.f, 0.f, 0.f, 0.f};

    #pragma unroll
    for (int ks = 0; ks < 8; ++ks) {
        s16x8 a;
        #pragma unroll
        for (int j = 0; j < 4; ++j) {
            a[j]     = (short)f2bf(au[ks][j]);
            a[j + 4] = (short)f2bf(av[ks][j]);
        }
        #pragma unroll
        for (int cf = 0; cf < 8; ++cf) {
            const int col = cf * 16 + lr;
            s16x8 b = *(const s16x8*)(blds +
                (size_t)(col * 32 + ((ks * 4 + lp) ^ (col & 7))) * 8);
            acc[cf] = __builtin_amdgcn_mfma_f32_16x16x32_bf16(a, b, acc[cf], 0, 0, 0);
        }
    }

    // epilogue: D map row=lp*4+i, col=lr. rb<H_EDGES is wave-uniform.
    if (rb < H_EDGES) {
        #pragma unroll
        for (int i = 0; i < 4; ++i) {
            const long gr = rb + lp * 4 + i;
            #pragma unroll
            for (int cf = 0; cf < 8; ++cf)
                qf[gr * FOUT + cf * 16 + lr] = acc[cf][i];
        }
    } else {
        #pragma unroll
        for (int i = 0; i < 4; ++i) {
            const long gr = rb + lp * 4 + i;
            if (gr < ROWS_TOTAL) {
                #pragma unroll
                for (int cf = 0; cf < 8; ++cf)
                    kb[(gr - H_EDGES) * FOUT + cf * 16 + lr] = f2bf(acc[cf][i]);
            }
        }
    }
}

// ---------- g2: per-edge attention, barrier-free waves ---------------------
// 1024 blocks x 256 thr = 4 edges/block, one 64-lane wave per edge.
// Each wave's LDS slice is private -> NO __syncthreads between phases
// (in-wave lgkmcnt ordering suffices); waves pipeline 16 independent
// edges/CU. One barrier before the 4-edge transpose store.
// k_l: packed [32 rows][16 slots of 16B], slot-XOR swizzle:
//   phys(m,sl) = m*16 + (sl&8) + ((sl&7)^(m&7))  -> conflict-free on
//   gather-write, score b128 reads, and per-element agg reads.
__global__ __launch_bounds__(256)
void g2_attn(const float* __restrict__ qf, const u16* __restrict__ kb,
             const int* __restrict__ col_idx, float* __restrict__ out) {
    __shared__ __align__(16) char smem[37888];
    const int t = threadIdx.x;
    const int w = t >> 6, l = t & 63;
    const int e = blockIdx.x * 4 + w;

    float (*tile)[4] = (float(*)[4])smem;            // [128][4] f32 = 2048 B
    char* base = smem + 2048 + w * 8960;             // per-wave slice
    u16*   kl  = (u16*)base;                         // 32x16 slots = 8192 B
    float* q_l = (float*)(base + 8192);              // 128 f32 = 512 B
    float* w_l = q_l + 128;                          // 32 f32
    int*   c_l = (int*)(w_l + 32);                   // 32 int

    if (l < DEG) c_l[l] = col_idx[(size_t)e * DEG + l];
    q_l[l]      = qf[(size_t)e * FOUT + l];
    q_l[l + 64] = qf[(size_t)e * FOUT + 64 + l];

    // gather 32 rows x 256B bf16 into swizzled slots (8 b128 per lane)
    #pragma unroll
    for (int it = 0; it < 8; ++it) {
        const int s = l + 64 * it;
        const int m = s >> 4, sl = s & 15;
        const int phys = m * 16 + (sl & 8) + ((sl & 7) ^ (m & 7));
        *(s16x8*)(kl + (size_t)phys * 8) =
            *(const s16x8*)(kb + (size_t)c_l[m] * FOUT + sl * 8);
    }

    // scores: 2 lanes per member, 64 elems each
    const int m = l >> 1, he = l & 1;
    float p = 0.f;
    #pragma unroll
    for (int j = 0; j < 8; ++j) {
        const int phys = m * 16 + he * 8 + (j ^ (m & 7));
        s16x8 kv = *(const s16x8*)(kl + (size_t)phys * 8);
        #pragma unroll
        for (int ee = 0; ee < 8; ++ee)
            p = fmaf(q_l[he * 64 + j * 8 + ee], bf2f((u16)kv[ee]), p);
    }
    p += __shfl_xor(p, 1);
    const float sc = p * 0.08838834764831845f;       // 1/sqrt(128)

    // dedup (first occurrence only) + softmax; pair lanes duplicate
    const int cm = c_l[m];
    bool valid = true;
    for (int j = 0; j < m; ++j)
        if (c_l[j] == cm) valid = false;
    const float sv = valid ? sc : -INFINITY;
    float mx = sv;
    #pragma unroll
    for (int d = 1; d < 64; d <<= 1) mx = fmaxf(mx, __shfl_xor(mx, d));
    const float ex = valid ? __expf(sv - mx) : 0.f;
    float sum = ex;
    #pragma unroll
    for (int d = 1; d < 64; d <<= 1) sum += __shfl_xor(sum, d);
    if (he == 0) w_l[m] = ex * 2.f / sum;            // 64-lane sum double-counts pairs

    // aggregate: lane l -> features l and l+64
    const int sl0 = l >> 3, el = l & 7;
    float a0 = 0.f, a1 = 0.f;
    #pragma unroll
    for (int mm = 0; mm < DEG; ++mm) {
        const float wv = w_l[mm];
        const int p0 = mm * 16 + (sl0 ^ (mm & 7));
        a0 = fmaf(wv, bf2f(kl[(size_t)p0 * 8 + el]), a0);
        a1 = fmaf(wv, bf2f(kl[(size_t)(p0 + 8) * 8 + el]), a1);
    }

    // micro-transpose: tile[f][edge-in-block], then float4 rows to out
    tile[l][w]      = a0;
    tile[l + 64][w] = a1;
    __syncthreads();
    if (t < FOUT) {
        f32x4 v = *(const f32x4*)tile[t];
        *(f32x4*)(out + (size_t)t * H_EDGES + blockIdx.x * 4) = v;
    }
}

extern "C" void kernel_launch(void* const* d_in, const int* in_sizes, int n_in,
                              void* d_out, int out_size, void* d_ws, size_t ws_size,
                              hipStream_t stream) {
    const float* hedge   = (const float*)d_in[0];
    const float* node    = (const float*)d_in[1];
    const float* Wq      = (const float*)d_in[2];
    const int*   col_idx = (const int*)d_in[4];   // row_idx (d_in[3]) == e/DEG by construction
    float* out = (float*)d_out;

    char* ws = (char*)d_ws;
    float* qf = (float*)ws;                                  // 4096*128 f32  = 2 MB
    u16*   kb = (u16*)(ws + (size_t)H_EDGES * FOUT * 4);     // 20000*128 bf16 = 5.12 MB
    u16*   bt = (u16*)(ws + (size_t)H_EDGES * FOUT * 4
                          + (size_t)N_NODES * FOUT * 2);     // 128*256 bf16 = 64 KB

    k0_prep<<<16, 256, 0, stream>>>(Wq, bt);
    g1_gemm<<<G1_BLOCKS, 256, 0, stream>>>(hedge, node, bt, qf, kb);
    g2_attn<<<H_EDGES / 4, 256, 0, stream>>>(qf, kb, col_idx, out);
}